// Round 9
// baseline (607.459 us; speedup 1.0000x reference)
//
#include <hip/hip_runtime.h>
#include <hip/hip_bf16.h>
#include <math.h>

#define D_MODEL 512
#define N_LAYERS 4
#define SEQ 2048
#define BATCH 8
#define M_TOT (BATCH * SEQ)   // 16384
#define DFF 2048
#define HEAD_V 256
#define SC 32                 // scan chunk
#define NC (SEQ / SC)         // 64 chunks

typedef __hip_bfloat16 bf16;
typedef __bf16 bf16x8 __attribute__((ext_vector_type(8)));
typedef float f32x4 __attribute__((ext_vector_type(4)));

__device__ __forceinline__ unsigned short bfbits(float x) {
    bf16 h = __float2bfloat16(x);
    return *(unsigned short*)&h;
}
__device__ __forceinline__ unsigned int pk(float a, float b) {
    return (unsigned int)bfbits(a) | ((unsigned int)bfbits(b) << 16);
}

// fast GELU: x*sigmoid(2*0.79788456*(x+0.044715x^3)) = x - x/(e+1), e=exp(2t)
// max abs err vs exact erf-GELU ~3e-3; inputs here are ~N(0,0.45) so err << bf16 noise.
__device__ __forceinline__ float gelu_f(float x) {
    float t2 = 1.5957691216f * (x + 0.044715f * x * x * x);
    float e = __expf(t2);
    return x - x * __builtin_amdgcn_rcpf(e + 1.0f);
}

// ---------- weight convert + transpose: W (R x C) f32 -> WT (C x R) bf16 ----
__global__ void convT_kernel(const float* __restrict__ W, bf16* __restrict__ WT,
                             int R, int C, size_t wstride, size_t tstride) {
    W += (size_t)blockIdx.z * wstride;
    WT += (size_t)blockIdx.z * tstride;
    __shared__ float t[32][33];
    int r0 = blockIdx.x * 32, c0 = blockIdx.y * 32;
    int tx = threadIdx.x, ty = threadIdx.y;  // 32 x 8
    #pragma unroll
    for (int i = 0; i < 32; i += 8)
        t[ty + i][tx] = W[(size_t)(r0 + ty + i) * C + c0 + tx];
    __syncthreads();
    #pragma unroll
    for (int i = 0; i < 32; i += 8)
        WT[(size_t)(c0 + ty + i) * R + r0 + tx] = __float2bfloat16(t[tx][ty + i]);
}

// ---------- embedding: x f32 + x bf16 --------------------------------------
__global__ void embed_kernel(const int* __restrict__ tokens,
                             const float* __restrict__ emb,
                             float* __restrict__ xf, bf16* __restrict__ xb) {
    int row = blockIdx.x, t = threadIdx.x;  // 128 threads
    int tok = tokens[row];
    float4 v = ((const float4*)(emb + (size_t)tok * D_MODEL))[t];
    ((float4*)(xf + (size_t)row * D_MODEL))[t] = v;
    uint2 st; st.x = pk(v.x, v.y); st.y = pk(v.z, v.w);
    ((uint2*)(xb + (size_t)row * D_MODEL))[t] = st;
}

// ---------- 3-phase parallel masked scan over S -----------------------------
__global__ void scanA_kernel(bf16* __restrict__ u, const int* __restrict__ tokens,
                             const float* __restrict__ decayp,
                             float* __restrict__ L, float* __restrict__ P) {
    int idx = blockIdx.x;                 // B*NC*2 blocks
    int dblk = idx & 1;
    int c = (idx >> 1) & (NC - 1);
    int b = idx >> 7;                     // NC*2 = 128
    int d = dblk * 256 + threadIdx.x;
    float decay = 1.0f / (1.0f + __expf(-decayp[0]));
    const int* tok = tokens + (size_t)b * SEQ + c * SC;
    bf16* up = u + ((size_t)b * SEQ + (size_t)c * SC) * D_MODEL + d;
    float mem = 0.0f;
    #pragma unroll 4
    for (int s = 0; s < SC; ++s) {
        float ui = __bfloat162float(up[(size_t)s * D_MODEL]);
        bool m = (tok[s] != 0);
        mem = (m ? decay : 1.0f) * mem + (m ? ui : 0.0f);
        up[(size_t)s * D_MODEL] = __float2bfloat16(mem);
    }
    L[((size_t)b * NC + c) * D_MODEL + d] = mem;
    if (threadIdx.x == 0 && dblk == 0) {
        int cnt = 0;
        for (int s = 0; s < SC; ++s) cnt += (tok[s] != 0);
        P[b * NC + c] = __powf(decay, (float)cnt);
    }
}

__global__ void scanB_kernel(const float* __restrict__ L, const float* __restrict__ P,
                             float* __restrict__ Mc) {
    int b = blockIdx.x >> 1;              // B*2 blocks
    int d = (blockIdx.x & 1) * 256 + threadIdx.x;
    float carry = 0.0f;
    for (int c = 0; c < NC; ++c) {
        size_t off = ((size_t)b * NC + c) * D_MODEL + d;
        Mc[off] = carry;
        carry = P[b * NC + c] * carry + L[off];
    }
}

__global__ void scanC_kernel(bf16* __restrict__ u, const int* __restrict__ tokens,
                             const float* __restrict__ decayp,
                             const float* __restrict__ Mc) {
    int idx = blockIdx.x;
    int dblk = idx & 1;
    int c = (idx >> 1) & (NC - 1);
    int b = idx >> 7;
    if (c == 0) return;
    int d = dblk * 256 + threadIdx.x;
    float decay = 1.0f / (1.0f + __expf(-decayp[0]));
    const int* tok = tokens + (size_t)b * SEQ + c * SC;
    bf16* up = u + ((size_t)b * SEQ + (size_t)c * SC) * D_MODEL + d;
    float carry = Mc[((size_t)b * NC + c) * D_MODEL + d];
    float coeff = 1.0f;
    #pragma unroll 4
    for (int s = 0; s < SC; ++s) {
        bool m = (tok[s] != 0);
        coeff *= (m ? decay : 1.0f);
        float local = __bfloat162float(up[(size_t)s * D_MODEL]);
        up[(size_t)s * D_MODEL] = __float2bfloat16(local + carry * coeff);
    }
}

// ---------- LayerNorm body + non-template wrappers --------------------------
__device__ __forceinline__ void ln_body(const float* __restrict__ in,
                                        float* __restrict__ outf,
                                        bf16* __restrict__ outb,
                                        const float* __restrict__ g,
                                        const float* __restrict__ b,
                                        int WF, int WB) {
    int w = threadIdx.x >> 6, lane = threadIdx.x & 63;
    int row = blockIdx.x * 4 + w;
    const float4* ip = (const float4*)(in + (size_t)row * D_MODEL);
    float4 v0 = ip[lane * 2], v1 = ip[lane * 2 + 1];
    float s1 = v0.x + v0.y + v0.z + v0.w + v1.x + v1.y + v1.z + v1.w;
    float s2 = v0.x * v0.x + v0.y * v0.y + v0.z * v0.z + v0.w * v0.w +
               v1.x * v1.x + v1.y * v1.y + v1.z * v1.z + v1.w * v1.w;
    #pragma unroll
    for (int off = 32; off; off >>= 1) {
        s1 += __shfl_xor(s1, off);
        s2 += __shfl_xor(s2, off);
    }
    float mu = s1 * (1.0f / D_MODEL);
    float var = s2 * (1.0f / D_MODEL) - mu * mu;
    float rstd = rsqrtf(var + 1e-5f);
    const float4* g4 = (const float4*)g;
    const float4* b4 = (const float4*)b;
    float4 g0 = g4[lane * 2], g1 = g4[lane * 2 + 1];
    float4 b0 = b4[lane * 2], b1 = b4[lane * 2 + 1];
    float4 o0, o1;
    o0.x = (v0.x - mu) * rstd * g0.x + b0.x;
    o0.y = (v0.y - mu) * rstd * g0.y + b0.y;
    o0.z = (v0.z - mu) * rstd * g0.z + b0.z;
    o0.w = (v0.w - mu) * rstd * g0.w + b0.w;
    o1.x = (v1.x - mu) * rstd * g1.x + b1.x;
    o1.y = (v1.y - mu) * rstd * g1.y + b1.y;
    o1.z = (v1.z - mu) * rstd * g1.z + b1.z;
    o1.w = (v1.w - mu) * rstd * g1.w + b1.w;
    if (WF) {
        float4* op = (float4*)(outf + (size_t)row * D_MODEL);
        op[lane * 2] = o0; op[lane * 2 + 1] = o1;
    }
    if (WB) {
        uint4 st;
        st.x = pk(o0.x, o0.y); st.y = pk(o0.z, o0.w);
        st.z = pk(o1.x, o1.y); st.w = pk(o1.z, o1.w);
        ((uint4*)(outb + (size_t)row * D_MODEL))[lane] = st;
    }
}

__global__ void ln_f32_kernel(const float* __restrict__ in, float* __restrict__ outf,
                              const float* __restrict__ g, const float* __restrict__ b) {
    ln_body(in, outf, nullptr, g, b, 1, 0);
}
__global__ void ln_b16_kernel(const float* __restrict__ in, bf16* __restrict__ outb,
                              const float* __restrict__ g, const float* __restrict__ b) {
    ln_body(in, nullptr, outb, g, b, 0, 1);
}

// ---------- bf16 MFMA GEMM: 256x128 tile, 128x64/wave, dbuf + T2 swizzle ----
// C(MxN) = A(MxK) @ BT(NxK)^T + bias; optional GELU, residual.
// OBF: 0 = f32 out, 1 = bf16 out, 2 = both.
// Per-wave 8x4 fragments of 16x16x32 -> LDS demand 0.0229 B/FLOP (below the
// 85 B/cyc ds_read_b128 ceiling at MFMA peak); 4x4 blocking was 0.031 and
// LDS-BW-bound at MfmaUtil 21% (rounds 6-8).
// LDS swizzle: phys = log ^ (((log>>7)&7)<<4); linear gload_lds dest,
// inverse-swizzled global source, same XOR on reads.
#define STAGE(s, k0)                                                          \
    do {                                                                      \
        _Pragma("unroll")                                                     \
        for (int it = 0; it < 4; ++it) {                                      \
            int c = tid + it * 256;                                           \
            int p = c * 16;                                                   \
            int l = p ^ (((p >> 7) & 7) << 4);                                \
            __builtin_amdgcn_global_load_lds(                                 \
                A + (size_t)(m0 + (l >> 6)) * K + (k0) + ((l & 63) >> 1),     \
                smem + (s) * ABYTES + (c & ~63) * 16, 16, 0, 0);              \
        }                                                                     \
        _Pragma("unroll")                                                     \
        for (int it = 0; it < LB; ++it) {                                     \
            int c = tid + it * 256;                                           \
            int p = c * 16;                                                   \
            int l = p ^ (((p >> 7) & 7) << 4);                                \
            __builtin_amdgcn_global_load_lds(                                 \
                BT + (size_t)(n0 + (l >> 6)) * K + (k0) + ((l & 63) >> 1),    \
                smem + 2 * ABYTES + (s) * BBYTES + (c & ~63) * 16, 16, 0, 0); \
        }                                                                     \
    } while (0)

template <int BN, int GELU, int RES, int OBF>
__device__ __forceinline__ void gemm_body(char* smem,
                          const bf16* __restrict__ A, const bf16* __restrict__ BT,
                          const float* __restrict__ bias, const float* __restrict__ R,
                          float* __restrict__ Cf, bf16* __restrict__ Cb,
                          int N, int K) {
    constexpr int NJ = BN / 32;               // n-frags per wave
    constexpr int MI = 8;                     // m-frags per wave (128 rows)
    constexpr int LB = BN / 64;
    constexpr int ABYTES = 256 * 32 * 2;      // 16 KB per stage
    constexpr int BBYTES = BN * 32 * 2;
    constexpr int ST = 16 * NJ + 4;           // epilogue LDS row stride (floats)
    const int tid = threadIdx.x;
    const int lane = tid & 63;
    const int w = tid >> 6, wr = w >> 1, wc = w & 1;
    const int lm = lane & 15, lk = lane >> 4;
    const int sw = ((lm >> 1) & 7) << 4;      // read-side swizzle XOR
    const int m0 = blockIdx.x * 256, n0 = blockIdx.y * BN;

    f32x4 acc[MI][NJ] = {};

    const int nt = K / 32;
    STAGE(0, 0);
    asm volatile("s_waitcnt vmcnt(0)" ::: "memory");
    __builtin_amdgcn_s_barrier();
    __builtin_amdgcn_sched_barrier(0);
    int cur = 0;
    for (int t = 0; t < nt; ++t) {
        if (t + 1 < nt) STAGE(cur ^ 1, (t + 1) * 32);
        const char* Asc = smem + cur * ABYTES;
        const char* Bsc = smem + 2 * ABYTES + cur * BBYTES;
        bf16x8 fa[MI], fb[NJ];
        #pragma unroll
        for (int i = 0; i < MI; ++i) {
            int la = (wr * 128 + i * 16 + lm) * 64 + lk * 16;
            fa[i] = *(const bf16x8*)(Asc + (la ^ sw));
        }
        #pragma unroll
        for (int j = 0; j < NJ; ++j) {
            int lb = (wc * (BN / 2) + j * 16 + lm) * 64 + lk * 16;
            fb[j] = *(const bf16x8*)(Bsc + (lb ^ sw));
        }
        #pragma unroll
        for (int i = 0; i < MI; ++i)
            #pragma unroll
            for (int j = 0; j < NJ; ++j)
                acc[i][j] = __builtin_amdgcn_mfma_f32_16x16x32_bf16(fa[i], fb[j], acc[i][j], 0, 0, 0);
        asm volatile("s_waitcnt vmcnt(0)" ::: "memory");
        __builtin_amdgcn_s_barrier();
        __builtin_amdgcn_sched_barrier(0);
        cur ^= 1;
    }

    // ---- epilogue: per-wave LDS round-trip for coalesced stores ----
    float* ep = (float*)smem + w * 16 * ST;
    const int r2 = lane >> 2;        // local row 0..15
    const int q = lane & 3;          // col quarter
    constexpr int CW = 16 * NJ;      // wave col width (= BN/2)
    const int gc0 = n0 + wc * CW + q * 4 * NJ;
    #pragma unroll
    for (int i = 0; i < MI; ++i) {
        #pragma unroll
        for (int j = 0; j < NJ; ++j)
            #pragma unroll
            for (int r = 0; r < 4; ++r)
                ep[(lk * 4 + r) * ST + j * 16 + lm] = acc[i][j][r];
        int grow = m0 + wr * 128 + i * 16 + r2;
        float4 fx[NJ];
        #pragma unroll
        for (int v = 0; v < NJ; ++v)
            fx[v] = *(const float4*)&ep[r2 * ST + q * 4 * NJ + v * 4];
        #pragma unroll
        for (int v = 0; v < NJ; ++v) {
            float4 bb = *(const float4*)(bias + gc0 + v * 4);
            fx[v].x += bb.x; fx[v].y += bb.y; fx[v].z += bb.z; fx[v].w += bb.w;
            if (GELU) {
                fx[v].x = gelu_f(fx[v].x);
                fx[v].y = gelu_f(fx[v].y);
                fx[v].z = gelu_f(fx[v].z);
                fx[v].w = gelu_f(fx[v].w);
            }
            if (RES) {
                float4 rr = *(const float4*)(R + (size_t)grow * N + gc0 + v * 4);
                fx[v].x += rr.x; fx[v].y += rr.y; fx[v].z += rr.z; fx[v].w += rr.w;
            }
        }
        if (OBF == 0 || OBF == 2) {
            #pragma unroll
            for (int v = 0; v < NJ; ++v)
                *(float4*)(Cf + (size_t)grow * N + gc0 + v * 4) = fx[v];
        }
        if (OBF >= 1) {
            #pragma unroll
            for (int v = 0; v < NJ; v += 2) {
                uint4 st;
                st.x = pk(fx[v].x, fx[v].y);
                st.y = pk(fx[v].z, fx[v].w);
                st.z = pk(fx[v + 1].x, fx[v + 1].y);
                st.w = pk(fx[v + 1].z, fx[v + 1].w);
                *(uint4*)(Cb + (size_t)grow * N + gc0 + v * 4) = st;
            }
        }
    }
}

#define DEF_GEMM(name, BN, GELU, RES, OBF)                                    \
__launch_bounds__(256, 2) __global__ void name(                               \
        const bf16* __restrict__ A, const bf16* __restrict__ BT,              \
        const float* __restrict__ bias, const float* __restrict__ R,          \
        float* __restrict__ Cf, bf16* __restrict__ Cb, int N, int K) {        \
    __shared__ char smem[2 * 16384 + 2 * (BN) * 64];                          \
    gemm_body<BN, GELU, RES, OBF>(smem, A, BT, bias, R, Cf, Cb, N, K);        \
}

DEF_GEMM(gemm_u,       128, 0, 0, 1)   // bf16 out
DEF_GEMM(gemm_res,     128, 0, 1, 0)   // f32 out + residual
DEF_GEMM(gemm_gelu,    128, 1, 0, 1)   // GELU, bf16 out
DEF_GEMM(gemm_resboth, 128, 0, 1, 2)   // residual, f32+bf16 out
DEF_GEMM(gemm64_plain,  64, 0, 0, 0)   // f32 out, narrow N (head)

extern "C" void kernel_launch(void* const* d_in, const int* in_sizes, int n_in,
                              void* d_out, int out_size, void* d_ws, size_t ws_size,
                              hipStream_t stream) {
    const int*   tokens = (const int*)d_in[0];
    const float* emb    = (const float*)d_in[1];
    const float* W_upd  = (const float*)d_in[2];
    const float* b_upd  = (const float*)d_in[3];
    const float* W_f    = (const float*)d_in[4];
    const float* b_f    = (const float*)d_in[5];
    const float* decayp = (const float*)d_in[6];
    const float* norm_g = (const float*)d_in[7];
    const float* norm_b = (const float*)d_in[8];
    const float* cms_g  = (const float*)d_in[9];
    const float* cms_b  = (const float*)d_in[10];
    const float* cW1    = (const float*)d_in[11];
    const float* cb1    = (const float*)d_in[12];
    const float* cW2    = (const float*)d_in[13];
    const float* cb2    = (const float*)d_in[14];
    const float* head_W = (const float*)d_in[15];
    const float* head_b = (const float*)d_in[16];
    float* out = (float*)d_out;

    const int M = M_TOT, D = D_MODEL, F = DFF, V = HEAD_V;

    // ---- workspace layout ----
    float* xf = (float*)d_ws;                                   // 33.55 MB f32 residual
    bf16*  lnb = (bf16*)((char*)d_ws + (size_t)M * D * 4);      // 16.78 MB bf16 A-operand
    bf16*  wb  = (bf16*)((char*)lnb + (size_t)M * D * 2);       // 18.09 MB bf16 weights^T
    const size_t WB_ELEMS = 9043968;
    char* dyn = (char*)wb + WB_ELEMS * 2;
    size_t used = (size_t)(dyn - (char*)d_ws);
    size_t avail = ws_size > used ? ws_size - used : 0;
    int MC = 4096;
    if (avail >= (size_t)16384 * F * 2) MC = 16384;
    else if (avail >= (size_t)8192 * F * 2) MC = 8192;
    bf16* ub = (bf16*)dyn;   // fastmem u/mems (M x D bf16), dead before layers
    bf16* hb = (bf16*)dyn;   // hidden chunk (MC x F bf16)

    // scan scratch lives in d_out (head GEMM fully overwrites it later)
    float* scanL = out;                            // B*NC*D f32 = 1.05 MB
    float* scanM = out + (size_t)BATCH * NC * D;   // 1.05 MB
    float* scanP = scanM + (size_t)BATCH * NC * D; // 2 KB

    bf16* WupdT = wb;                 // 512x512
    bf16* WfT   = wb + 262144;        // 512x512
    bf16* W1T   = wb + 524288;        // per layer 2048x512 (F x D)
    bf16* W2T   = wb + 4718592;       // per layer 512x2048 (D x F)
    bf16* HWT   = wb + 8912896;       // 256x512

    dim3 tb(32, 8);
    convT_kernel<<<dim3(16, 16, 2), tb, 0, stream>>>(W_upd, WupdT, D, D,
                                                     (size_t)(W_f - W_upd), 262144);
    convT_kernel<<<dim3(16, 64, N_LAYERS), tb, 0, stream>>>(cW1, W1T, D, F,
                                                            (size_t)D * F, 1048576);
    convT_kernel<<<dim3(64, 16, N_LAYERS), tb, 0, stream>>>(cW2, W2T, F, D,
                                                            (size_t)F * D, 1048576);
    convT_kernel<<<dim3(16, 8, 1), tb, 0, stream>>>(head_W, HWT, D, V, 0, 0);

    // 1. embedding (f32 + bf16)
    embed_kernel<<<M, 128, 0, stream>>>(tokens, emb, xf, lnb);

    // 2. fast memory
    gemm_u<<<dim3(M / 256, D / 128), 256, 0, stream>>>(
        lnb, WupdT, b_upd, nullptr, nullptr, ub, D, D);
    scanA_kernel<<<BATCH * NC * 2, 256, 0, stream>>>(ub, tokens, decayp, scanL, scanP);
    scanB_kernel<<<BATCH * 2, 256, 0, stream>>>(scanL, scanP, scanM);
    scanC_kernel<<<BATCH * NC * 2, 256, 0, stream>>>(ub, tokens, decayp, scanM);
    gemm_res<<<dim3(M / 256, D / 128), 256, 0, stream>>>(
        ub, WfT, b_f, xf, xf, nullptr, D, D);
    ln_f32_kernel<<<M / 4, 256, 0, stream>>>(xf, xf, norm_g, norm_b);

    // 3. CMS layers
    for (int l = 0; l < N_LAYERS; ++l) {
        ln_b16_kernel<<<M / 4, 256, 0, stream>>>(xf, lnb,
                                                 cms_g + (size_t)l * D,
                                                 cms_b + (size_t)l * D);
        bool last = (l == N_LAYERS - 1);
        for (int mc = 0; mc < M; mc += MC) {
            gemm_gelu<<<dim3(MC / 256, F / 128), 256, 0, stream>>>(
                lnb + (size_t)mc * D, W1T + (size_t)l * 1048576,
                cb1 + (size_t)l * F, nullptr, nullptr, hb, F, D);
            if (last)
                gemm_resboth<<<dim3(MC / 256, D / 128), 256, 0, stream>>>(
                    hb, W2T + (size_t)l * 1048576, cb2 + (size_t)l * D,
                    xf + (size_t)mc * D, xf + (size_t)mc * D,
                    lnb + (size_t)mc * D, D, F);
            else
                gemm_res<<<dim3(MC / 256, D / 128), 256, 0, stream>>>(
                    hb, W2T + (size_t)l * 1048576, cb2 + (size_t)l * D,
                    xf + (size_t)mc * D, xf + (size_t)mc * D, nullptr, D, F);
        }
    }

    // 4. head (reads bf16 copy written by last W2 epilogue)
    gemm64_plain<<<dim3(M / 256, V / 64), 256, 0, stream>>>(
        lnb, HWT, head_b, nullptr, out, nullptr, V, D);
}

// Round 10
// 554.887 us; speedup vs baseline: 1.0947x; 1.0947x over previous
//
#include <hip/hip_runtime.h>
#include <hip/hip_bf16.h>
#include <math.h>

#define D_MODEL 512
#define N_LAYERS 4
#define SEQ 2048
#define BATCH 8
#define M_TOT (BATCH * SEQ)   // 16384
#define DFF 2048
#define HEAD_V 256
#define SC 32                 // scan chunk
#define NC (SEQ / SC)         // 64 chunks

typedef __hip_bfloat16 bf16;
typedef __bf16 bf16x8 __attribute__((ext_vector_type(8)));
typedef float f32x4 __attribute__((ext_vector_type(4)));

__device__ __forceinline__ unsigned short bfbits(float x) {
    bf16 h = __float2bfloat16(x);
    return *(unsigned short*)&h;
}
__device__ __forceinline__ unsigned int pk(float a, float b) {
    return (unsigned int)bfbits(a) | ((unsigned int)bfbits(b) << 16);
}

// fast GELU (sigmoid form): max abs err vs exact ~3e-3 (passed round 9, absmax 0.0156)
__device__ __forceinline__ float gelu_f(float x) {
    float t2 = 1.5957691216f * (x + 0.044715f * x * x * x);
    float e = __expf(t2);
    return x - x * __builtin_amdgcn_rcpf(e + 1.0f);
}

// ---------- weight convert + transpose: W (R x C) f32 -> WT (C x R) bf16 ----
__global__ void convT_kernel(const float* __restrict__ W, bf16* __restrict__ WT,
                             int R, int C, size_t wstride, size_t tstride) {
    W += (size_t)blockIdx.z * wstride;
    WT += (size_t)blockIdx.z * tstride;
    __shared__ float t[32][33];
    int r0 = blockIdx.x * 32, c0 = blockIdx.y * 32;
    int tx = threadIdx.x, ty = threadIdx.y;  // 32 x 8
    #pragma unroll
    for (int i = 0; i < 32; i += 8)
        t[ty + i][tx] = W[(size_t)(r0 + ty + i) * C + c0 + tx];
    __syncthreads();
    #pragma unroll
    for (int i = 0; i < 32; i += 8)
        WT[(size_t)(c0 + ty + i) * R + r0 + tx] = __float2bfloat16(t[tx][ty + i]);
}

// ---------- embedding: x f32 + x bf16 --------------------------------------
__global__ void embed_kernel(const int* __restrict__ tokens,
                             const float* __restrict__ emb,
                             float* __restrict__ xf, bf16* __restrict__ xb) {
    int row = blockIdx.x, t = threadIdx.x;  // 128 threads
    int tok = tokens[row];
    float4 v = ((const float4*)(emb + (size_t)tok * D_MODEL))[t];
    ((float4*)(xf + (size_t)row * D_MODEL))[t] = v;
    uint2 st; st.x = pk(v.x, v.y); st.y = pk(v.z, v.w);
    ((uint2*)(xb + (size_t)row * D_MODEL))[t] = st;
}

// ---------- 3-phase parallel masked scan over S -----------------------------
__global__ void scanA_kernel(bf16* __restrict__ u, const int* __restrict__ tokens,
                             const float* __restrict__ decayp,
                             float* __restrict__ L, float* __restrict__ P) {
    int idx = blockIdx.x;                 // B*NC*2 blocks
    int dblk = idx & 1;
    int c = (idx >> 1) & (NC - 1);
    int b = idx >> 7;                     // NC*2 = 128
    int d = dblk * 256 + threadIdx.x;
    float decay = 1.0f / (1.0f + __expf(-decayp[0]));
    const int* tok = tokens + (size_t)b * SEQ + c * SC;
    bf16* up = u + ((size_t)b * SEQ + (size_t)c * SC) * D_MODEL + d;
    float mem = 0.0f;
    #pragma unroll 4
    for (int s = 0; s < SC; ++s) {
        float ui = __bfloat162float(up[(size_t)s * D_MODEL]);
        bool m = (tok[s] != 0);
        mem = (m ? decay : 1.0f) * mem + (m ? ui : 0.0f);
        up[(size_t)s * D_MODEL] = __float2bfloat16(mem);
    }
    L[((size_t)b * NC + c) * D_MODEL + d] = mem;
    if (threadIdx.x == 0 && dblk == 0) {
        int cnt = 0;
        for (int s = 0; s < SC; ++s) cnt += (tok[s] != 0);
        P[b * NC + c] = __powf(decay, (float)cnt);
    }
}

__global__ void scanB_kernel(const float* __restrict__ L, const float* __restrict__ P,
                             float* __restrict__ Mc) {
    int b = blockIdx.x >> 1;              // B*2 blocks
    int d = (blockIdx.x & 1) * 256 + threadIdx.x;
    float carry = 0.0f;
    for (int c = 0; c < NC; ++c) {
        size_t off = ((size_t)b * NC + c) * D_MODEL + d;
        Mc[off] = carry;
        carry = P[b * NC + c] * carry + L[off];
    }
}

__global__ void scanC_kernel(bf16* __restrict__ u, const int* __restrict__ tokens,
                             const float* __restrict__ decayp,
                             const float* __restrict__ Mc) {
    int idx = blockIdx.x;
    int dblk = idx & 1;
    int c = (idx >> 1) & (NC - 1);
    int b = idx >> 7;
    if (c == 0) return;
    int d = dblk * 256 + threadIdx.x;
    float decay = 1.0f / (1.0f + __expf(-decayp[0]));
    const int* tok = tokens + (size_t)b * SEQ + c * SC;
    bf16* up = u + ((size_t)b * SEQ + (size_t)c * SC) * D_MODEL + d;
    float carry = Mc[((size_t)b * NC + c) * D_MODEL + d];
    float coeff = 1.0f;
    #pragma unroll 4
    for (int s = 0; s < SC; ++s) {
        bool m = (tok[s] != 0);
        coeff *= (m ? decay : 1.0f);
        float local = __bfloat162float(up[(size_t)s * D_MODEL]);
        up[(size_t)s * D_MODEL] = __float2bfloat16(local + carry * coeff);
    }
}

// ---------- LayerNorm body + non-template wrappers --------------------------
__device__ __forceinline__ void ln_body(const float* __restrict__ in,
                                        float* __restrict__ outf,
                                        bf16* __restrict__ outb,
                                        const float* __restrict__ g,
                                        const float* __restrict__ b,
                                        int WF, int WB) {
    int w = threadIdx.x >> 6, lane = threadIdx.x & 63;
    int row = blockIdx.x * 4 + w;
    const float4* ip = (const float4*)(in + (size_t)row * D_MODEL);
    float4 v0 = ip[lane * 2], v1 = ip[lane * 2 + 1];
    float s1 = v0.x + v0.y + v0.z + v0.w + v1.x + v1.y + v1.z + v1.w;
    float s2 = v0.x * v0.x + v0.y * v0.y + v0.z * v0.z + v0.w * v0.w +
               v1.x * v1.x + v1.y * v1.y + v1.z * v1.z + v1.w * v1.w;
    #pragma unroll
    for (int off = 32; off; off >>= 1) {
        s1 += __shfl_xor(s1, off);
        s2 += __shfl_xor(s2, off);
    }
    float mu = s1 * (1.0f / D_MODEL);
    float var = s2 * (1.0f / D_MODEL) - mu * mu;
    float rstd = rsqrtf(var + 1e-5f);
    const float4* g4 = (const float4*)g;
    const float4* b4 = (const float4*)b;
    float4 g0 = g4[lane * 2], g1 = g4[lane * 2 + 1];
    float4 b0 = b4[lane * 2], b1 = b4[lane * 2 + 1];
    float4 o0, o1;
    o0.x = (v0.x - mu) * rstd * g0.x + b0.x;
    o0.y = (v0.y - mu) * rstd * g0.y + b0.y;
    o0.z = (v0.z - mu) * rstd * g0.z + b0.z;
    o0.w = (v0.w - mu) * rstd * g0.w + b0.w;
    o1.x = (v1.x - mu) * rstd * g1.x + b1.x;
    o1.y = (v1.y - mu) * rstd * g1.y + b1.y;
    o1.z = (v1.z - mu) * rstd * g1.z + b1.z;
    o1.w = (v1.w - mu) * rstd * g1.w + b1.w;
    if (WF) {
        float4* op = (float4*)(outf + (size_t)row * D_MODEL);
        op[lane * 2] = o0; op[lane * 2 + 1] = o1;
    }
    if (WB) {
        uint4 st;
        st.x = pk(o0.x, o0.y); st.y = pk(o0.z, o0.w);
        st.z = pk(o1.x, o1.y); st.w = pk(o1.z, o1.w);
        ((uint4*)(outb + (size_t)row * D_MODEL))[lane] = st;
    }
}

__global__ void ln_f32_kernel(const float* __restrict__ in, float* __restrict__ outf,
                              const float* __restrict__ g, const float* __restrict__ b) {
    ln_body(in, outf, nullptr, g, b, 1, 0);
}
__global__ void ln_b16_kernel(const float* __restrict__ in, bf16* __restrict__ outb,
                              const float* __restrict__ g, const float* __restrict__ b) {
    ln_body(in, nullptr, outb, g, b, 0, 1);
}

// ---------- bf16 MFMA GEMM: 8-phase-style schedule (m201 port) --------------
// BM=256, BN=128, BK=64, 512 threads (8 waves: wr 2 x wc 4), per-wave 128x32.
// 4 phases per K-tile: {ds_read subtile || stage part of tile t+2 -> barrier
// -> lgkmcnt(0) -> setprio(1) 8 MFMA setprio(0) -> barrier}. 3 LDS buffers
// (3 x 48KB), counted vmcnt(6) ONCE per tile (6 stage instrs/wave/tile, next
// tile's 6 stay in flight) -- no drain in steady state.
// Swizzle: LDS row = 128B; phys slot = logical slot ^ (row&7). gload_lds dest
// linear; global source inverse-swizzled; reads apply same XOR -> 2-way (free).
#define BUFB 49152

#define STAGE_A(buf, k0)                                                      \
    do {                                                                      \
        _Pragma("unroll")                                                     \
        for (int it = 0; it < 4; ++it) {                                      \
            int c = tid + it * 512;                                           \
            int r = c >> 3, s = c & 7;                                        \
            __builtin_amdgcn_global_load_lds(                                 \
                A + (size_t)(m0 + r) * K + (k0) + 8 * (s ^ (r & 7)),          \
                smem + (buf) * BUFB + c * 16, 16, 0, 0);                      \
        }                                                                     \
    } while (0)

#define STAGE_B(buf, k0)                                                      \
    do {                                                                      \
        _Pragma("unroll")                                                     \
        for (int it = 0; it < 2; ++it) {                                      \
            int c = tid + it * 512;                                           \
            int r = c >> 3, s = c & 7;                                        \
            __builtin_amdgcn_global_load_lds(                                 \
                BT + (size_t)(n0 + r) * K + (k0) + 8 * (s ^ (r & 7)),         \
                smem + (buf) * BUFB + 32768 + c * 16, 16, 0, 0);              \
        }                                                                     \
    } while (0)

#define LOAD_FA(IH, KS)                                                       \
    do {                                                                      \
        fa0 = *(const bf16x8*)(Ab + (wr * 128 + ((IH) * 4 + 0) * 16 + lm) * 128 + (((KS) * 64 + lk * 16) ^ swz)); \
        fa1 = *(const bf16x8*)(Ab + (wr * 128 + ((IH) * 4 + 1) * 16 + lm) * 128 + (((KS) * 64 + lk * 16) ^ swz)); \
        fa2 = *(const bf16x8*)(Ab + (wr * 128 + ((IH) * 4 + 2) * 16 + lm) * 128 + (((KS) * 64 + lk * 16) ^ swz)); \
        fa3 = *(const bf16x8*)(Ab + (wr * 128 + ((IH) * 4 + 3) * 16 + lm) * 128 + (((KS) * 64 + lk * 16) ^ swz)); \
    } while (0)

#define LOAD_FB(KS)                                                           \
    do {                                                                      \
        fb0 = *(const bf16x8*)(Bb + (wc * 32 + 0 + lm) * 128 + (((KS) * 64 + lk * 16) ^ swz)); \
        fb1 = *(const bf16x8*)(Bb + (wc * 32 + 16 + lm) * 128 + (((KS) * 64 + lk * 16) ^ swz)); \
    } while (0)

#define MFMA8(B0)                                                             \
    do {                                                                      \
        acc[(B0) + 0][0] = __builtin_amdgcn_mfma_f32_16x16x32_bf16(fa0, fb0, acc[(B0) + 0][0], 0, 0, 0); \
        acc[(B0) + 0][1] = __builtin_amdgcn_mfma_f32_16x16x32_bf16(fa0, fb1, acc[(B0) + 0][1], 0, 0, 0); \
        acc[(B0) + 1][0] = __builtin_amdgcn_mfma_f32_16x16x32_bf16(fa1, fb0, acc[(B0) + 1][0], 0, 0, 0); \
        acc[(B0) + 1][1] = __builtin_amdgcn_mfma_f32_16x16x32_bf16(fa1, fb1, acc[(B0) + 1][1], 0, 0, 0); \
        acc[(B0) + 2][0] = __builtin_amdgcn_mfma_f32_16x16x32_bf16(fa2, fb0, acc[(B0) + 2][0], 0, 0, 0); \
        acc[(B0) + 2][1] = __builtin_amdgcn_mfma_f32_16x16x32_bf16(fa2, fb1, acc[(B0) + 2][1], 0, 0, 0); \
        acc[(B0) + 3][0] = __builtin_amdgcn_mfma_f32_16x16x32_bf16(fa3, fb0, acc[(B0) + 3][0], 0, 0, 0); \
        acc[(B0) + 3][1] = __builtin_amdgcn_mfma_f32_16x16x32_bf16(fa3, fb1, acc[(B0) + 3][1], 0, 0, 0); \
    } while (0)

#define PHASE_PRE                                                             \
    do {                                                                      \
        __builtin_amdgcn_s_barrier();                                         \
        asm volatile("s_waitcnt lgkmcnt(0)" ::: "memory");                    \
        __builtin_amdgcn_sched_barrier(0);                                    \
        __builtin_amdgcn_s_setprio(1);                                        \
    } while (0)

#define PHASE_POST                                                            \
    do {                                                                      \
        __builtin_amdgcn_s_setprio(0);                                        \
        __builtin_amdgcn_s_barrier();                                         \
    } while (0)

template <int GELU, int RES, int OBF>
__device__ __forceinline__ void gemm_body(char* smem,
                          const bf16* __restrict__ A, const bf16* __restrict__ BT,
                          const float* __restrict__ bias, const float* __restrict__ R,
                          float* __restrict__ Cf, bf16* __restrict__ Cb,
                          int N, int K) {
    constexpr int ST = 36;                    // epilogue LDS row stride (floats)
    const int tid = threadIdx.x;
    const int lane = tid & 63;
    const int w = tid >> 6;                   // 0..7
    const int wr = w >> 2, wc = w & 3;        // 2 x 4
    const int lm = lane & 15, lk = lane >> 4;
    const int swz = (lm & 7) << 4;
    const int m0 = blockIdx.x * 256, n0 = blockIdx.y * 128;

    f32x4 acc[8][2] = {};
    const int nt = K / 64;                    // all shapes: nt >= 4

    STAGE_A(0, 0); STAGE_B(0, 0);
    STAGE_A(1, 64); STAGE_B(1, 64);
    asm volatile("s_waitcnt vmcnt(6)" ::: "memory");
    __builtin_amdgcn_s_barrier();
    __builtin_amdgcn_sched_barrier(0);

    int cur = 0;
    for (int t = 0; t < nt; ++t) {
        const char* Ab = smem + cur * BUFB;
        const char* Bb = Ab + 32768;
        int nb = cur + 2; if (nb >= 3) nb -= 3;
        bf16x8 fa0, fa1, fa2, fa3, fb0, fb1;
        // phase 0: ks=0, A rows 0..63 of wave's half; stage A(t+2)
        LOAD_FB(0);
        LOAD_FA(0, 0);
        if (t + 2 < nt) STAGE_A(nb, (t + 2) * 64);
        PHASE_PRE;
        MFMA8(0);
        PHASE_POST;
        // phase 1: ks=0, A rows 64..127; stage B(t+2)
        LOAD_FA(1, 0);
        if (t + 2 < nt) STAGE_B(nb, (t + 2) * 64);
        PHASE_PRE;
        MFMA8(4);
        PHASE_POST;
        // phase 2: ks=1, A rows 0..63
        LOAD_FB(1);
        LOAD_FA(0, 1);
        PHASE_PRE;
        MFMA8(0);
        PHASE_POST;
        // phase 3: ks=1, A rows 64..127; counted wait for tile t+1's buffer
        LOAD_FA(1, 1);
        PHASE_PRE;
        MFMA8(4);
        __builtin_amdgcn_s_setprio(0);
        if (t + 2 < nt) asm volatile("s_waitcnt vmcnt(6)" ::: "memory");
        else            asm volatile("s_waitcnt vmcnt(0)" ::: "memory");
        __builtin_amdgcn_s_barrier();
        __builtin_amdgcn_sched_barrier(0);
        cur = (cur == 2) ? 0 : cur + 1;
    }

    // ---- epilogue: per-wave LDS round-trip for coalesced stores ----
    float* ep = (float*)smem + w * 16 * ST;
    const int r2 = lane >> 2;        // local row 0..15
    const int q = lane & 3;          // col quarter (8 floats each)
    const int gc0 = n0 + wc * 32 + q * 8;
    #pragma unroll
    for (int i = 0; i < 8; ++i) {
        #pragma unroll
        for (int j = 0; j < 2; ++j)
            #pragma unroll
            for (int r = 0; r < 4; ++r)
                ep[(lk * 4 + r) * ST + j * 16 + lm] = acc[i][j][r];
        int grow = m0 + wr * 128 + i * 16 + r2;
        float4 fx[2];
        #pragma unroll
        for (int v = 0; v < 2; ++v)
            fx[v] = *(const float4*)&ep[r2 * ST + q * 8 + v * 4];
        #pragma unroll
        for (int v = 0; v < 2; ++v) {
            float4 bb = *(const float4*)(bias + gc0 + v * 4);
            fx[v].x += bb.x; fx[v].y += bb.y; fx[v].z += bb.z; fx[v].w += bb.w;
            if (GELU) {
                fx[v].x = gelu_f(fx[v].x);
                fx[v].y = gelu_f(fx[v].y);
                fx[v].z = gelu_f(fx[v].z);
                fx[v].w = gelu_f(fx[v].w);
            }
            if (RES) {
                float4 rr = *(const float4*)(R + (size_t)grow * N + gc0 + v * 4);
                fx[v].x += rr.x; fx[v].y += rr.y; fx[v].z += rr.z; fx[v].w += rr.w;
            }
        }
        if (OBF == 0 || OBF == 2) {
            #pragma unroll
            for (int v = 0; v < 2; ++v)
                *(float4*)(Cf + (size_t)grow * N + gc0 + v * 4) = fx[v];
        }
        if (OBF >= 1) {
            uint4 st;
            st.x = pk(fx[0].x, fx[0].y);
            st.y = pk(fx[0].z, fx[0].w);
            st.z = pk(fx[1].x, fx[1].y);
            st.w = pk(fx[1].z, fx[1].w);
            *(uint4*)(Cb + (size_t)grow * N + gc0) = st;
        }
    }
}

#define DEF_GEMM(name, GELU, RES, OBF)                                        \
__launch_bounds__(512) __global__ void name(                                  \
        const bf16* __restrict__ A, const bf16* __restrict__ BT,              \
        const float* __restrict__ bias, const float* __restrict__ R,          \
        float* __restrict__ Cf, bf16* __restrict__ Cb, int N, int K) {        \
    __shared__ char smem[3 * BUFB];                                           \
    gemm_body<GELU, RES, OBF>(smem, A, BT, bias, R, Cf, Cb, N, K);            \
}

DEF_GEMM(gemm_u,       0, 0, 1)   // bf16 out
DEF_GEMM(gemm_res,     0, 1, 0)   // f32 out + residual
DEF_GEMM(gemm_gelu,    1, 0, 1)   // GELU, bf16 out
DEF_GEMM(gemm_resboth, 0, 1, 2)   // residual, f32+bf16 out
DEF_GEMM(gemm_plain,   0, 0, 0)   // f32 out

extern "C" void kernel_launch(void* const* d_in, const int* in_sizes, int n_in,
                              void* d_out, int out_size, void* d_ws, size_t ws_size,
                              hipStream_t stream) {
    const int*   tokens = (const int*)d_in[0];
    const float* emb    = (const float*)d_in[1];
    const float* W_upd  = (const float*)d_in[2];
    const float* b_upd  = (const float*)d_in[3];
    const float* W_f    = (const float*)d_in[4];
    const float* b_f    = (const float*)d_in[5];
    const float* decayp = (const float*)d_in[6];
    const float* norm_g = (const float*)d_in[7];
    const float* norm_b = (const float*)d_in[8];
    const float* cms_g  = (const float*)d_in[9];
    const float* cms_b  = (const float*)d_in[10];
    const float* cW1    = (const float*)d_in[11];
    const float* cb1    = (const float*)d_in[12];
    const float* cW2    = (const float*)d_in[13];
    const float* cb2    = (const float*)d_in[14];
    const float* head_W = (const float*)d_in[15];
    const float* head_b = (const float*)d_in[16];
    float* out = (float*)d_out;

    const int M = M_TOT, D = D_MODEL, F = DFF, V = HEAD_V;

    // ---- workspace layout ----
    float* xf = (float*)d_ws;                                   // 33.55 MB f32 residual
    bf16*  lnb = (bf16*)((char*)d_ws + (size_t)M * D * 4);      // 16.78 MB bf16 A-operand
    bf16*  wb  = (bf16*)((char*)lnb + (size_t)M * D * 2);       // 18.09 MB bf16 weights^T
    const size_t WB_ELEMS = 9043968;
    char* dyn = (char*)wb + WB_ELEMS * 2;
    size_t used = (size_t)(dyn - (char*)d_ws);
    size_t avail = ws_size > used ? ws_size - used : 0;
    int MC = 4096;
    if (avail >= (size_t)16384 * F * 2) MC = 16384;
    else if (avail >= (size_t)8192 * F * 2) MC = 8192;
    bf16* ub = (bf16*)dyn;   // fastmem u/mems (M x D bf16), dead before layers
    bf16* hb = (bf16*)dyn;   // hidden chunk (MC x F bf16)

    // scan scratch lives in d_out (head GEMM fully overwrites it later)
    float* scanL = out;                            // B*NC*D f32 = 1.05 MB
    float* scanM = out + (size_t)BATCH * NC * D;   // 1.05 MB
    float* scanP = scanM + (size_t)BATCH * NC * D; // 2 KB

    bf16* WupdT = wb;                 // 512x512
    bf16* WfT   = wb + 262144;        // 512x512
    bf16* W1T   = wb + 524288;        // per layer 2048x512 (F x D)
    bf16* W2T   = wb + 4718592;       // per layer 512x2048 (D x F)
    bf16* HWT   = wb + 8912896;       // 256x512

    dim3 tb(32, 8);
    convT_kernel<<<dim3(16, 16, 2), tb, 0, stream>>>(W_upd, WupdT, D, D,
                                                     (size_t)(W_f - W_upd), 262144);
    convT_kernel<<<dim3(16, 64, N_LAYERS), tb, 0, stream>>>(cW1, W1T, D, F,
                                                            (size_t)D * F, 1048576);
    convT_kernel<<<dim3(64, 16, N_LAYERS), tb, 0, stream>>>(cW2, W2T, F, D,
                                                            (size_t)F * D, 1048576);
    convT_kernel<<<dim3(16, 8, 1), tb, 0, stream>>>(head_W, HWT, D, V, 0, 0);

    // 1. embedding (f32 + bf16)
    embed_kernel<<<M, 128, 0, stream>>>(tokens, emb, xf, lnb);

    // 2. fast memory
    gemm_u<<<dim3(M / 256, D / 128), 512, 0, stream>>>(
        lnb, WupdT, b_upd, nullptr, nullptr, ub, D, D);
    scanA_kernel<<<BATCH * NC * 2, 256, 0, stream>>>(ub, tokens, decayp, scanL, scanP);
    scanB_kernel<<<BATCH * 2, 256, 0, stream>>>(scanL, scanP, scanM);
    scanC_kernel<<<BATCH * NC * 2, 256, 0, stream>>>(ub, tokens, decayp, scanM);
    gemm_res<<<dim3(M / 256, D / 128), 512, 0, stream>>>(
        ub, WfT, b_f, xf, xf, nullptr, D, D);
    ln_f32_kernel<<<M / 4, 256, 0, stream>>>(xf, xf, norm_g, norm_b);

    // 3. CMS layers
    for (int l = 0; l < N_LAYERS; ++l) {
        ln_b16_kernel<<<M / 4, 256, 0, stream>>>(xf, lnb,
                                                 cms_g + (size_t)l * D,
                                                 cms_b + (size_t)l * D);
        bool last = (l == N_LAYERS - 1);
        for (int mc = 0; mc < M; mc += MC) {
            gemm_gelu<<<dim3(MC / 256, F / 128), 512, 0, stream>>>(
                lnb + (size_t)mc * D, W1T + (size_t)l * 1048576,
                cb1 + (size_t)l * F, nullptr, nullptr, hb, F, D);
            if (last)
                gemm_resboth<<<dim3(MC / 256, D / 128), 512, 0, stream>>>(
                    hb, W2T + (size_t)l * 1048576, cb2 + (size_t)l * D,
                    xf + (size_t)mc * D, xf + (size_t)mc * D,
                    lnb + (size_t)mc * D, D, F);
            else
                gemm_res<<<dim3(MC / 256, D / 128), 512, 0, stream>>>(
                    hb, W2T + (size_t)l * 1048576, cb2 + (size_t)l * D,
                    xf + (size_t)mc * D, xf + (size_t)mc * D, nullptr, D, F);
        }
    }

    // 4. head (reads bf16 copy written by last W2 epilogue)
    gemm_plain<<<dim3(M / 256, V / 128), 512, 0, stream>>>(
        lnb, HWT, head_b, nullptr, out, nullptr, V, D);
}

// Round 11
// 539.123 us; speedup vs baseline: 1.1268x; 1.0292x over previous
//
#include <hip/hip_runtime.h>
#include <hip/hip_bf16.h>
#include <math.h>

#define D_MODEL 512
#define N_LAYERS 4
#define SEQ 2048
#define BATCH 8
#define M_TOT (BATCH * SEQ)   // 16384
#define DFF 2048
#define HEAD_V 256
#define SC 32                 // scan chunk
#define NC (SEQ / SC)         // 64 chunks

typedef __hip_bfloat16 bf16;
typedef __bf16 bf16x8 __attribute__((ext_vector_type(8)));
typedef float f32x4 __attribute__((ext_vector_type(4)));

__device__ __forceinline__ unsigned short bfbits(float x) {
    bf16 h = __float2bfloat16(x);
    return *(unsigned short*)&h;
}
__device__ __forceinline__ unsigned int pk(float a, float b) {
    return (unsigned int)bfbits(a) | ((unsigned int)bfbits(b) << 16);
}

// fast GELU (sigmoid form): max abs err vs exact ~3e-3 (validated r9/r10, absmax 0.0156)
__device__ __forceinline__ float gelu_f(float x) {
    float t2 = 1.5957691216f * (x + 0.044715f * x * x * x);
    float e = __expf(t2);
    return x - x * __builtin_amdgcn_rcpf(e + 1.0f);
}

// ---------- weight convert + transpose: W (R x C) f32 -> WT (C x R) bf16 ----
__global__ void convT_kernel(const float* __restrict__ W, bf16* __restrict__ WT,
                             int R, int C, size_t wstride, size_t tstride) {
    W += (size_t)blockIdx.z * wstride;
    WT += (size_t)blockIdx.z * tstride;
    __shared__ float t[32][33];
    int r0 = blockIdx.x * 32, c0 = blockIdx.y * 32;
    int tx = threadIdx.x, ty = threadIdx.y;  // 32 x 8
    #pragma unroll
    for (int i = 0; i < 32; i += 8)
        t[ty + i][tx] = W[(size_t)(r0 + ty + i) * C + c0 + tx];
    __syncthreads();
    #pragma unroll
    for (int i = 0; i < 32; i += 8)
        WT[(size_t)(c0 + ty + i) * R + r0 + tx] = __float2bfloat16(t[tx][ty + i]);
}

// ---------- embedding: x f32 + x bf16 --------------------------------------
__global__ void embed_kernel(const int* __restrict__ tokens,
                             const float* __restrict__ emb,
                             float* __restrict__ xf, bf16* __restrict__ xb) {
    int row = blockIdx.x, t = threadIdx.x;  // 128 threads
    int tok = tokens[row];
    float4 v = ((const float4*)(emb + (size_t)tok * D_MODEL))[t];
    ((float4*)(xf + (size_t)row * D_MODEL))[t] = v;
    uint2 st; st.x = pk(v.x, v.y); st.y = pk(v.z, v.w);
    ((uint2*)(xb + (size_t)row * D_MODEL))[t] = st;
}

// ---------- 3-phase parallel masked scan over S -----------------------------
__global__ void scanA_kernel(bf16* __restrict__ u, const int* __restrict__ tokens,
                             const float* __restrict__ decayp,
                             float* __restrict__ L, float* __restrict__ P) {
    int idx = blockIdx.x;                 // B*NC*2 blocks
    int dblk = idx & 1;
    int c = (idx >> 1) & (NC - 1);
    int b = idx >> 7;                     // NC*2 = 128
    int d = dblk * 256 + threadIdx.x;
    float decay = 1.0f / (1.0f + __expf(-decayp[0]));
    const int* tok = tokens + (size_t)b * SEQ + c * SC;
    bf16* up = u + ((size_t)b * SEQ + (size_t)c * SC) * D_MODEL + d;
    float mem = 0.0f;
    #pragma unroll 4
    for (int s = 0; s < SC; ++s) {
        float ui = __bfloat162float(up[(size_t)s * D_MODEL]);
        bool m = (tok[s] != 0);
        mem = (m ? decay : 1.0f) * mem + (m ? ui : 0.0f);
        up[(size_t)s * D_MODEL] = __float2bfloat16(mem);
    }
    L[((size_t)b * NC + c) * D_MODEL + d] = mem;
    if (threadIdx.x == 0 && dblk == 0) {
        int cnt = 0;
        for (int s = 0; s < SC; ++s) cnt += (tok[s] != 0);
        P[b * NC + c] = __powf(decay, (float)cnt);
    }
}

__global__ void scanB_kernel(const float* __restrict__ L, const float* __restrict__ P,
                             float* __restrict__ Mc) {
    int b = blockIdx.x >> 1;              // B*2 blocks
    int d = (blockIdx.x & 1) * 256 + threadIdx.x;
    float carry = 0.0f;
    for (int c = 0; c < NC; ++c) {
        size_t off = ((size_t)b * NC + c) * D_MODEL + d;
        Mc[off] = carry;
        carry = P[b * NC + c] * carry + L[off];
    }
}

__global__ void scanC_kernel(bf16* __restrict__ u, const int* __restrict__ tokens,
                             const float* __restrict__ decayp,
                             const float* __restrict__ Mc) {
    int idx = blockIdx.x;
    int dblk = idx & 1;
    int c = (idx >> 1) & (NC - 1);
    int b = idx >> 7;
    if (c == 0) return;
    int d = dblk * 256 + threadIdx.x;
    float decay = 1.0f / (1.0f + __expf(-decayp[0]));
    const int* tok = tokens + (size_t)b * SEQ + c * SC;
    bf16* up = u + ((size_t)b * SEQ + (size_t)c * SC) * D_MODEL + d;
    float carry = Mc[((size_t)b * NC + c) * D_MODEL + d];
    float coeff = 1.0f;
    #pragma unroll 4
    for (int s = 0; s < SC; ++s) {
        bool m = (tok[s] != 0);
        coeff *= (m ? decay : 1.0f);
        float local = __bfloat162float(up[(size_t)s * D_MODEL]);
        up[(size_t)s * D_MODEL] = __float2bfloat16(local + carry * coeff);
    }
}

// ---------- LayerNorm body + non-template wrappers --------------------------
__device__ __forceinline__ void ln_body(const float* __restrict__ in,
                                        float* __restrict__ outf,
                                        bf16* __restrict__ outb,
                                        const float* __restrict__ g,
                                        const float* __restrict__ b,
                                        int WF, int WB) {
    int w = threadIdx.x >> 6, lane = threadIdx.x & 63;
    int row = blockIdx.x * 4 + w;
    const float4* ip = (const float4*)(in + (size_t)row * D_MODEL);
    float4 v0 = ip[lane * 2], v1 = ip[lane * 2 + 1];
    float s1 = v0.x + v0.y + v0.z + v0.w + v1.x + v1.y + v1.z + v1.w;
    float s2 = v0.x * v0.x + v0.y * v0.y + v0.z * v0.z + v0.w * v0.w +
               v1.x * v1.x + v1.y * v1.y + v1.z * v1.z + v1.w * v1.w;
    #pragma unroll
    for (int off = 32; off; off >>= 1) {
        s1 += __shfl_xor(s1, off);
        s2 += __shfl_xor(s2, off);
    }
    float mu = s1 * (1.0f / D_MODEL);
    float var = s2 * (1.0f / D_MODEL) - mu * mu;
    float rstd = rsqrtf(var + 1e-5f);
    const float4* g4 = (const float4*)g;
    const float4* b4 = (const float4*)b;
    float4 g0 = g4[lane * 2], g1 = g4[lane * 2 + 1];
    float4 b0 = b4[lane * 2], b1 = b4[lane * 2 + 1];
    float4 o0, o1;
    o0.x = (v0.x - mu) * rstd * g0.x + b0.x;
    o0.y = (v0.y - mu) * rstd * g0.y + b0.y;
    o0.z = (v0.z - mu) * rstd * g0.z + b0.z;
    o0.w = (v0.w - mu) * rstd * g0.w + b0.w;
    o1.x = (v1.x - mu) * rstd * g1.x + b1.x;
    o1.y = (v1.y - mu) * rstd * g1.y + b1.y;
    o1.z = (v1.z - mu) * rstd * g1.z + b1.z;
    o1.w = (v1.w - mu) * rstd * g1.w + b1.w;
    if (WF) {
        float4* op = (float4*)(outf + (size_t)row * D_MODEL);
        op[lane * 2] = o0; op[lane * 2 + 1] = o1;
    }
    if (WB) {
        uint4 st;
        st.x = pk(o0.x, o0.y); st.y = pk(o0.z, o0.w);
        st.z = pk(o1.x, o1.y); st.w = pk(o1.z, o1.w);
        ((uint4*)(outb + (size_t)row * D_MODEL))[lane] = st;
    }
}

__global__ void ln_f32_kernel(const float* __restrict__ in, float* __restrict__ outf,
                              const float* __restrict__ g, const float* __restrict__ b) {
    ln_body(in, outf, nullptr, g, b, 1, 0);
}
__global__ void ln_b16_kernel(const float* __restrict__ in, bf16* __restrict__ outb,
                              const float* __restrict__ g, const float* __restrict__ b) {
    ln_body(in, nullptr, outb, g, b, 0, 1);
}

// ---------- bf16 MFMA GEMM: high-ratio waves + counted-vmcnt dbuf -----------
// Geometry: BN=256 always, 512 threads (8 waves, 2x4). WM = per-wave rows:
//   WM=128 -> BM=256, per-wave 128x64: 24 ds_read / 64 MFMA / K-tile (0.0234 B/FLOP)
//   WM=64  -> BM=128, per-wave  64x64: 16 ds_read / 32 MFMA (grid stays >=256 blocks)
// Schedule per K-tile: [stage t+1 (AL+4 gload_lds)] -> vmcnt(AL+4) (t's loads
// done, t+1's stay IN FLIGHT - no drain) -> barrier -> ds_read+MFMA clusters
// (compiler-scheduled lgkmcnt, setprio around MFMA) -> barrier. 2 buffers.
// Swizzle: LDS row = 128B; 16B-slot s holds chunk s^(row&7); reads XOR same.
#define STAGE(buf, k0)                                                        \
    do {                                                                      \
        _Pragma("unroll")                                                     \
        for (int it = 0; it < AL; ++it) {                                     \
            int cc = tid + it * 512;                                          \
            int rr = cc >> 3, ss = cc & 7;                                    \
            __builtin_amdgcn_global_load_lds(                                 \
                A + (size_t)(m0 + rr) * K + (k0) + 8 * (ss ^ (rr & 7)),       \
                smem + (buf) * TILEB + cc * 16, 16, 0, 0);                    \
        }                                                                     \
        _Pragma("unroll")                                                     \
        for (int it = 0; it < 4; ++it) {                                      \
            int cc = tid + it * 512;                                          \
            int rr = cc >> 3, ss = cc & 7;                                    \
            __builtin_amdgcn_global_load_lds(                                 \
                BT + (size_t)(n0 + rr) * K + (k0) + 8 * (ss ^ (rr & 7)),      \
                smem + (buf) * TILEB + BM * 128 + cc * 16, 16, 0, 0);         \
        }                                                                     \
    } while (0)

template <int WM, int GELU, int RES, int OBF>
__device__ __forceinline__ void gemm_body(char* smem,
                          const bf16* __restrict__ A, const bf16* __restrict__ BT,
                          const float* __restrict__ bias, const float* __restrict__ R,
                          float* __restrict__ Cf, bf16* __restrict__ Cb,
                          int N, int K) {
    constexpr int BM = 2 * WM;
    constexpr int MI = WM / 16;               // m-frags per wave: 8 or 4
    constexpr int AL = BM / 64;               // A gload_lds per thread per tile
    constexpr int TILEB = (BM + 256) * 128;   // bytes per LDS buffer
    constexpr int ST = 68;                    // epilogue LDS row stride (floats)
    const int tid = threadIdx.x;
    const int lane = tid & 63;
    const int w = tid >> 6;
    const int wr = w >> 2, wc = w & 3;        // 2 x 4 wave grid
    const int lm = lane & 15, lk = lane >> 4;
    const int swz = (lm & 7) << 4;
    const int m0 = blockIdx.x * BM, n0 = blockIdx.y * 256;

    f32x4 acc[MI][4] = {};
    const int nt = K >> 6;

    STAGE(0, 0);
    int cur = 0;
    for (int t = 0; t < nt; ++t) {
        if (t + 1 < nt) {
            STAGE(cur ^ 1, (t + 1) * 64);
            if constexpr (AL == 4) asm volatile("s_waitcnt vmcnt(8)" ::: "memory");
            else                   asm volatile("s_waitcnt vmcnt(6)" ::: "memory");
        } else {
            asm volatile("s_waitcnt vmcnt(0)" ::: "memory");
        }
        __builtin_amdgcn_s_barrier();
        __builtin_amdgcn_sched_barrier(0);
        const char* Ab = smem + cur * TILEB;
        const char* Bb = Ab + BM * 128;
        #pragma unroll
        for (int ks = 0; ks < 2; ++ks) {
            bf16x8 fb[4];
            #pragma unroll
            for (int nf = 0; nf < 4; ++nf)
                fb[nf] = *(const bf16x8*)(Bb + (wc * 64 + nf * 16 + lm) * 128 +
                                          ((ks * 64 + lk * 16) ^ swz));
            #pragma unroll
            for (int mh = 0; mh < MI / 4; ++mh) {
                bf16x8 fa[4];
                #pragma unroll
                for (int mf = 0; mf < 4; ++mf)
                    fa[mf] = *(const bf16x8*)(Ab + (wr * WM + (mh * 4 + mf) * 16 + lm) * 128 +
                                              ((ks * 64 + lk * 16) ^ swz));
                __builtin_amdgcn_s_setprio(1);
                #pragma unroll
                for (int mf = 0; mf < 4; ++mf)
                    #pragma unroll
                    for (int nf = 0; nf < 4; ++nf)
                        acc[mh * 4 + mf][nf] = __builtin_amdgcn_mfma_f32_16x16x32_bf16(
                            fa[mf], fb[nf], acc[mh * 4 + mf][nf], 0, 0, 0);
                __builtin_amdgcn_s_setprio(0);
            }
        }
        __builtin_amdgcn_s_barrier();
        cur ^= 1;
    }
    __syncthreads();

    // ---- epilogue: per-wave LDS round-trip for coalesced stores ----
    float* ep = (float*)smem + w * 16 * ST;
    const int r2 = lane >> 2;        // local row 0..15
    const int q = lane & 3;          // 16-col group
    const int gc0 = n0 + wc * 64 + q * 16;
    #pragma unroll
    for (int i = 0; i < MI; ++i) {
        #pragma unroll
        for (int nf = 0; nf < 4; ++nf)
            #pragma unroll
            for (int r = 0; r < 4; ++r)
                ep[(lk * 4 + r) * ST + nf * 16 + lm] = acc[i][nf][r];
        int grow = m0 + wr * WM + i * 16 + r2;
        float4 fx[4];
        #pragma unroll
        for (int v = 0; v < 4; ++v)
            fx[v] = *(const float4*)&ep[r2 * ST + q * 16 + v * 4];
        #pragma unroll
        for (int v = 0; v < 4; ++v) {
            float4 bb = *(const float4*)(bias + gc0 + v * 4);
            fx[v].x += bb.x; fx[v].y += bb.y; fx[v].z += bb.z; fx[v].w += bb.w;
            if (GELU) {
                fx[v].x = gelu_f(fx[v].x);
                fx[v].y = gelu_f(fx[v].y);
                fx[v].z = gelu_f(fx[v].z);
                fx[v].w = gelu_f(fx[v].w);
            }
            if (RES) {
                float4 rr = *(const float4*)(R + (size_t)grow * N + gc0 + v * 4);
                fx[v].x += rr.x; fx[v].y += rr.y; fx[v].z += rr.z; fx[v].w += rr.w;
            }
        }
        if (OBF == 0 || OBF == 2) {
            #pragma unroll
            for (int v = 0; v < 4; ++v)
                *(float4*)(Cf + (size_t)grow * N + gc0 + v * 4) = fx[v];
        }
        if (OBF >= 1) {
            uint4 s1, s2;
            s1.x = pk(fx[0].x, fx[0].y); s1.y = pk(fx[0].z, fx[0].w);
            s1.z = pk(fx[1].x, fx[1].y); s1.w = pk(fx[1].z, fx[1].w);
            s2.x = pk(fx[2].x, fx[2].y); s2.y = pk(fx[2].z, fx[2].w);
            s2.z = pk(fx[3].x, fx[3].y); s2.w = pk(fx[3].z, fx[3].w);
            *(uint4*)(Cb + (size_t)grow * N + gc0) = s1;
            *(uint4*)(Cb + (size_t)grow * N + gc0 + 8) = s2;
        }
    }
}

#define DEF_GEMM(name, WM, GELU, RES, OBF)                                    \
__launch_bounds__(512) __global__ void name(                                  \
        const bf16* __restrict__ A, const bf16* __restrict__ BT,              \
        const float* __restrict__ bias, const float* __restrict__ R,          \
        float* __restrict__ Cf, bf16* __restrict__ Cb, int N, int K) {        \
    __shared__ char smem[2 * ((2 * (WM)) + 256) * 128];                       \
    gemm_body<WM, GELU, RES, OBF>(smem, A, BT, bias, R, Cf, Cb, N, K);        \
}

DEF_GEMM(gemm_gelu,    128, 1, 0, 1)   // W1: 256x256, GELU, bf16 out
DEF_GEMM(gemm_u,        64, 0, 0, 1)   // fastmem u: 128x256, bf16 out
DEF_GEMM(gemm_res,      64, 0, 1, 0)   // W2/fastmem: 128x256, f32 + residual
DEF_GEMM(gemm_resboth,  64, 0, 1, 2)   // last W2: residual, f32+bf16 out
DEF_GEMM(gemm_plain,    64, 0, 0, 0)   // head: 128x256, f32 out

extern "C" void kernel_launch(void* const* d_in, const int* in_sizes, int n_in,
                              void* d_out, int out_size, void* d_ws, size_t ws_size,
                              hipStream_t stream) {
    const int*   tokens = (const int*)d_in[0];
    const float* emb    = (const float*)d_in[1];
    const float* W_upd  = (const float*)d_in[2];
    const float* b_upd  = (const float*)d_in[3];
    const float* W_f    = (const float*)d_in[4];
    const float* b_f    = (const float*)d_in[5];
    const float* decayp = (const float*)d_in[6];
    const float* norm_g = (const float*)d_in[7];
    const float* norm_b = (const float*)d_in[8];
    const float* cms_g  = (const float*)d_in[9];
    const float* cms_b  = (const float*)d_in[10];
    const float* cW1    = (const float*)d_in[11];
    const float* cb1    = (const float*)d_in[12];
    const float* cW2    = (const float*)d_in[13];
    const float* cb2    = (const float*)d_in[14];
    const float* head_W = (const float*)d_in[15];
    const float* head_b = (const float*)d_in[16];
    float* out = (float*)d_out;

    const int M = M_TOT, D = D_MODEL, F = DFF, V = HEAD_V;

    // ---- workspace layout ----
    float* xf = (float*)d_ws;                                   // 33.55 MB f32 residual
    bf16*  lnb = (bf16*)((char*)d_ws + (size_t)M * D * 4);      // 16.78 MB bf16 A-operand
    bf16*  wb  = (bf16*)((char*)lnb + (size_t)M * D * 2);       // 18.09 MB bf16 weights^T
    const size_t WB_ELEMS = 9043968;
    char* dyn = (char*)wb + WB_ELEMS * 2;
    size_t used = (size_t)(dyn - (char*)d_ws);
    size_t avail = ws_size > used ? ws_size - used : 0;
    int MC = 4096;
    if (avail >= (size_t)16384 * F * 2) MC = 16384;
    else if (avail >= (size_t)8192 * F * 2) MC = 8192;
    bf16* ub = (bf16*)dyn;   // fastmem u/mems (M x D bf16), dead before layers
    bf16* hb = (bf16*)dyn;   // hidden chunk (MC x F bf16)

    // scan scratch lives in d_out (head GEMM fully overwrites it later)
    float* scanL = out;                            // B*NC*D f32 = 1.05 MB
    float* scanM = out + (size_t)BATCH * NC * D;   // 1.05 MB
    float* scanP = scanM + (size_t)BATCH * NC * D; // 2 KB

    bf16* WupdT = wb;                 // 512x512
    bf16* WfT   = wb + 262144;        // 512x512
    bf16* W1T   = wb + 524288;        // per layer 2048x512 (F x D)
    bf16* W2T   = wb + 4718592;       // per layer 512x2048 (D x F)
    bf16* HWT   = wb + 8912896;       // 256x512

    dim3 tb(32, 8);
    convT_kernel<<<dim3(16, 16, 2), tb, 0, stream>>>(W_upd, WupdT, D, D,
                                                     (size_t)(W_f - W_upd), 262144);
    convT_kernel<<<dim3(16, 64, N_LAYERS), tb, 0, stream>>>(cW1, W1T, D, F,
                                                            (size_t)D * F, 1048576);
    convT_kernel<<<dim3(64, 16, N_LAYERS), tb, 0, stream>>>(cW2, W2T, F, D,
                                                            (size_t)F * D, 1048576);
    convT_kernel<<<dim3(16, 8, 1), tb, 0, stream>>>(head_W, HWT, D, V, 0, 0);

    // 1. embedding (f32 + bf16)
    embed_kernel<<<M, 128, 0, stream>>>(tokens, emb, xf, lnb);

    // 2. fast memory
    gemm_u<<<dim3(M / 128, D / 256), 512, 0, stream>>>(
        lnb, WupdT, b_upd, nullptr, nullptr, ub, D, D);
    scanA_kernel<<<BATCH * NC * 2, 256, 0, stream>>>(ub, tokens, decayp, scanL, scanP);
    scanB_kernel<<<BATCH * 2, 256, 0, stream>>>(scanL, scanP, scanM);
    scanC_kernel<<<BATCH * NC * 2, 256, 0, stream>>>(ub, tokens, decayp, scanM);
    gemm_res<<<dim3(M / 128, D / 256), 512, 0, stream>>>(
        ub, WfT, b_f, xf, xf, nullptr, D, D);
    ln_f32_kernel<<<M / 4, 256, 0, stream>>>(xf, xf, norm_g, norm_b);

    // 3. CMS layers
    for (int l = 0; l < N_LAYERS; ++l) {
        ln_b16_kernel<<<M / 4, 256, 0, stream>>>(xf, lnb,
                                                 cms_g + (size_t)l * D,
                                                 cms_b + (size_t)l * D);
        bool last = (l == N_LAYERS - 1);
        for (int mc = 0; mc < M; mc += MC) {
            gemm_gelu<<<dim3(MC / 256, F / 256), 512, 0, stream>>>(
                lnb + (size_t)mc * D, W1T + (size_t)l * 1048576,
                cb1 + (size_t)l * F, nullptr, nullptr, hb, F, D);
            if (last)
                gemm_resboth<<<dim3(MC / 128, D / 256), 512, 0, stream>>>(
                    hb, W2T + (size_t)l * 1048576, cb2 + (size_t)l * D,
                    xf + (size_t)mc * D, xf + (size_t)mc * D,
                    lnb + (size_t)mc * D, D, F);
            else
                gemm_res<<<dim3(MC / 128, D / 256), 512, 0, stream>>>(
                    hb, W2T + (size_t)l * 1048576, cb2 + (size_t)l * D,
                    xf + (size_t)mc * D, xf + (size_t)mc * D, nullptr, D, F);
        }
    }

    // 4. head (reads bf16 copy written by last W2 epilogue)
    gemm_plain<<<dim3(M / 128, V / 256), 512, 0, stream>>>(
        lnb, HWT, head_b, nullptr, out, nullptr, V, D);
}